// Round 4
// baseline (3385.086 us; speedup 1.0000x reference)
//
#include <hip/hip_runtime.h>
#include <math.h>

#define B_TOT 2048
#define T_LEN 512
#define HDIM 64
#define FC1 50

typedef __bf16 bf16x8 __attribute__((ext_vector_type(8)));
typedef float f32x4 __attribute__((ext_vector_type(4)));
typedef unsigned int u32x4 __attribute__((ext_vector_type(4)));
typedef unsigned short u16x8 __attribute__((ext_vector_type(8)));

__device__ __forceinline__ float sigm(float x) { return 1.0f / (1.0f + __expf(-x)); }
__device__ __forceinline__ float tanh_(float x) { return 2.0f / (1.0f + __expf(-2.0f * x)) - 1.0f; }

// Raw barrier: drain LDS only (ds_write visibility), NOT vmcnt — global seq
// stores have no intra-kernel consumer (next layer = next kernel) and prefetch
// loads are waited at use via data deps. __syncthreads()'s vmcnt(0) drain was
// ~2500 cy/step in R3 (measured 3300 cy/step vs ~700 cy of work).
#define BARRIER() asm volatile("s_waitcnt lgkmcnt(0)\n\ts_barrier" ::: "memory")

// LSTM layer via bf16 MFMA, split-precision state (h = hi + lo bf16, packed
// into one u32 = hi | lo<<16) — identical arithmetic to R3 (absmax 1.22e-4).
// Block = 16 batch rows, 4 waves; wave w owns units [16w, 16w+16).
// A-frag: lane row m = lane&15, k-slot (c=lane>>4, e): k = kk*32 + 8c + e.
// B-frag: same phi for k => hardware k-permutation cancels.
// C/D: col = lane&15, row = 4*(lane>>4) + reg.
#define STEP(T0, P)                                                            \
  {                                                                            \
    const int swz = (nn & 7) << 2;                                             \
    bf16x8 ahh[2], ahl[2];                                                     \
    _Pragma("unroll")                                                          \
    for (int kk = 0; kk < 2; ++kk) {                                           \
      int ub = kk * 32 + 8 * cg;                                               \
      u32x4 p0 = *(const u32x4*)&hbuf[P][nn * 64 + ((ub + 0) ^ swz)];          \
      u32x4 p1 = *(const u32x4*)&hbuf[P][nn * 64 + ((ub + 4) ^ swz)];          \
      u16x8 uh, ul;                                                            \
      _Pragma("unroll")                                                        \
      for (int e = 0; e < 4; ++e) {                                            \
        uh[e]     = (unsigned short)(p0[e] & 0xffffu);                         \
        ul[e]     = (unsigned short)(p0[e] >> 16);                             \
        uh[4 + e] = (unsigned short)(p1[e] & 0xffffu);                         \
        ul[4 + e] = (unsigned short)(p1[e] >> 16);                             \
      }                                                                        \
      ahh[kk] = __builtin_bit_cast(bf16x8, uh);                                \
      ahl[kk] = __builtin_bit_cast(bf16x8, ul);                                \
    }                                                                          \
    bf16x8 axh[2], axl[2];                                                     \
    if (!FIRST) {                                                              \
      _Pragma("unroll")                                                        \
      for (int kk = 0; kk < 2; ++kk) {                                         \
        u32x4 q0 = xpk[P][2 * kk + 0];                                         \
        u32x4 q1 = xpk[P][2 * kk + 1];                                         \
        u16x8 uh, ul;                                                          \
        _Pragma("unroll")                                                      \
        for (int e = 0; e < 4; ++e) {                                          \
          uh[e]     = (unsigned short)(q0[e] & 0xffffu);                       \
          ul[e]     = (unsigned short)(q0[e] >> 16);                           \
          uh[4 + e] = (unsigned short)(q1[e] & 0xffffu);                       \
          ul[4 + e] = (unsigned short)(q1[e] >> 16);                           \
        }                                                                      \
        axh[kk] = __builtin_bit_cast(bf16x8, uh);                              \
        axl[kk] = __builtin_bit_cast(bf16x8, ul);                              \
      }                                                                        \
    }                                                                          \
    f32x4 accs[4];                                                             \
    _Pragma("unroll")                                                          \
    for (int g = 0; g < 4; ++g) {                                              \
      f32x4 a = {0.f, 0.f, 0.f, 0.f};                                         \
      a = __builtin_amdgcn_mfma_f32_16x16x32_bf16(ahh[0], bhh[g][0], a, 0, 0, 0); \
      a = __builtin_amdgcn_mfma_f32_16x16x32_bf16(ahh[1], bhh[g][1], a, 0, 0, 0); \
      a = __builtin_amdgcn_mfma_f32_16x16x32_bf16(ahl[0], bhh[g][0], a, 0, 0, 0); \
      a = __builtin_amdgcn_mfma_f32_16x16x32_bf16(ahl[1], bhh[g][1], a, 0, 0, 0); \
      if (!FIRST) {                                                            \
        a = __builtin_amdgcn_mfma_f32_16x16x32_bf16(axh[0], bih[g][0], a, 0, 0, 0); \
        a = __builtin_amdgcn_mfma_f32_16x16x32_bf16(axh[1], bih[g][1], a, 0, 0, 0); \
        a = __builtin_amdgcn_mfma_f32_16x16x32_bf16(axl[0], bih[g][0], a, 0, 0, 0); \
        a = __builtin_amdgcn_mfma_f32_16x16x32_bf16(axl[1], bih[g][1], a, 0, 0, 0); \
      }                                                                        \
      accs[g] = a;                                                             \
    }                                                                          \
    float xcur[12];                                                            \
    if (FIRST) {                                                               \
      _Pragma("unroll")                                                        \
      for (int q = 0; q < 12; ++q) xcur[q] = xr[P][q];                         \
    }                                                                          \
    /* prefetch t+2 into parity slot P (consumed 2 steps later) */             \
    {                                                                          \
      int tp = (T0) + 2; if (tp >= T_LEN) tp = T_LEN - 1;                      \
      if (FIRST) {                                                             \
        _Pragma("unroll")                                                      \
        for (int r = 0; r < 4; ++r)                                            \
          _Pragma("unroll")                                                    \
          for (int i = 0; i < 3; ++i)                                          \
            xr[P][r * 3 + i] =                                                 \
                x_f32[((size_t)(bbase + 4 * cg + r) * T_LEN + tp) * 3 + i];    \
      } else {                                                                 \
        const unsigned int* px = seqp + xrow + (size_t)tp * HDIM;              \
        xpk[P][0] = *(const u32x4*)(px + xcol);                                \
        xpk[P][1] = *(const u32x4*)(px + xcol + 4);                            \
        xpk[P][2] = *(const u32x4*)(px + 32 + xcol);                           \
        xpk[P][3] = *(const u32x4*)(px + 32 + xcol + 4);                       \
      }                                                                        \
    }                                                                          \
    /* epilogue: gates, cell update, h split+pack+store */                     \
    _Pragma("unroll")                                                          \
    for (int r = 0; r < 4; ++r) {                                              \
      float gi = accs[0][r] + bias[0];                                         \
      float gf = accs[1][r] + bias[1];                                         \
      float gg = accs[2][r] + bias[2];                                         \
      float go = accs[3][r] + bias[3];                                         \
      if (FIRST) {                                                             \
        gi += xw[0] * xcur[r*3+0] + xw[1]  * xcur[r*3+1] + xw[2]  * xcur[r*3+2]; \
        gf += xw[3] * xcur[r*3+0] + xw[4]  * xcur[r*3+1] + xw[5]  * xcur[r*3+2]; \
        gg += xw[6] * xcur[r*3+0] + xw[7]  * xcur[r*3+1] + xw[8]  * xcur[r*3+2]; \
        go += xw[9] * xcur[r*3+0] + xw[10] * xcur[r*3+1] + xw[11] * xcur[r*3+2]; \
      }                                                                        \
      float iv = sigm(gi), fv = sigm(gf), gv = tanh_(gg), ov = sigm(go);       \
      cell[r] = fv * cell[r] + iv * gv;                                        \
      float hv = ov * tanh_(cell[r]);                                          \
      __bf16 h1 = (__bf16)hv;                                                  \
      __bf16 h2 = (__bf16)(hv - (float)h1);                                    \
      unsigned int hb = (unsigned int)__builtin_bit_cast(unsigned short, h1)   \
                      | ((unsigned int)__builtin_bit_cast(unsigned short, h2) << 16); \
      int mrow = 4 * cg + r;                                                   \
      hbuf[1 - (P)][mrow * 64 + (uu ^ ((mrow & 7) << 2))] = hb;                \
      size_t oidx = ((size_t)(bbase + mrow) * T_LEN + (T0)) * HDIM + uu;       \
      seqp[oidx] = hb;                                                         \
    }                                                                          \
    BARRIER();                                                                 \
  }

template<bool FIRST>
__global__ __launch_bounds__(256, 1)
void lstm_mfma(const float* __restrict__ x_f32,  // FIRST only: [B,T,3] f32
               const float* __restrict__ w_ih,   // FIRST: [256,3] else [256,64]
               const float* __restrict__ w_hh,   // [256,64]
               const float* __restrict__ b_ih,   // [256]
               const float* __restrict__ b_hh,   // [256]
               unsigned int* seqp)               // [B,T,64] packed hi|lo<<16 (in-place for mid)
{
    const int tid  = threadIdx.x;
    const int lane = tid & 63;
    const int wv   = tid >> 6;
    const int nn   = lane & 15;     // A-row m / B-col n / D-col
    const int cg   = lane >> 4;     // k-group, D row group
    const int bbase = blockIdx.x * 16;
    const int uu = 16 * wv + nn;

    __shared__ __align__(16) unsigned int hbuf[2][16 * 64];

    bf16x8 bhh[4][2];
    const int grow = 16 * wv + nn;
#pragma unroll
    for (int g = 0; g < 4; ++g)
#pragma unroll
      for (int kk = 0; kk < 2; ++kk) {
        const float* wp = w_hh + (size_t)(64 * g + grow) * 64 + kk * 32 + 8 * cg;
#pragma unroll
        for (int e = 0; e < 8; ++e) bhh[g][kk][e] = (__bf16)wp[e];
      }
    bf16x8 bih[4][2];
    float xw[12];
    if (FIRST) {
#pragma unroll
      for (int g = 0; g < 4; ++g)
#pragma unroll
        for (int i = 0; i < 3; ++i) xw[g * 3 + i] = w_ih[(64 * g + grow) * 3 + i];
    } else {
#pragma unroll
      for (int g = 0; g < 4; ++g)
#pragma unroll
        for (int kk = 0; kk < 2; ++kk) {
          const float* wp = w_ih + (size_t)(64 * g + grow) * 64 + kk * 32 + 8 * cg;
#pragma unroll
          for (int e = 0; e < 8; ++e) bih[g][kk][e] = (__bf16)wp[e];
        }
    }
    float bias[4];
#pragma unroll
    for (int g = 0; g < 4; ++g) {
      int row = 64 * g + grow;
      bias[g] = b_ih[row] + b_hh[row];
    }

#pragma unroll
    for (int q = 0; q < 4; ++q) hbuf[0][tid * 4 + q] = 0u;

    float cell[4] = {0.f, 0.f, 0.f, 0.f};

    const size_t xrow = (size_t)(bbase + nn) * T_LEN * HDIM;
    const int xcol = 8 * cg;
    u32x4 xpk[2][4];
    float xr[2][12];
    if (FIRST) {
#pragma unroll
      for (int p = 0; p < 2; ++p)
#pragma unroll
        for (int r = 0; r < 4; ++r)
#pragma unroll
          for (int i = 0; i < 3; ++i)
            xr[p][r * 3 + i] = x_f32[((size_t)(bbase + 4 * cg + r) * T_LEN + p) * 3 + i];
    } else {
#pragma unroll
      for (int p = 0; p < 2; ++p) {
        const unsigned int* px = seqp + xrow + (size_t)p * HDIM;
        xpk[p][0] = *(const u32x4*)(px + xcol);
        xpk[p][1] = *(const u32x4*)(px + xcol + 4);
        xpk[p][2] = *(const u32x4*)(px + 32 + xcol);
        xpk[p][3] = *(const u32x4*)(px + 32 + xcol + 4);
      }
    }
    __syncthreads();

    for (int t = 0; t < T_LEN; t += 2) {
      STEP(t, 0);
      STEP(t + 1, 1);
    }
}

// FC head: out[b] = fc2_b + fc2_w . relu(fc1_b + fc1_w . h_T[b])
__global__ __launch_bounds__(256, 1)
void fc_head(const unsigned int* __restrict__ seqp,
             const float* __restrict__ fc1_w, const float* __restrict__ fc1_b,
             const float* __restrict__ fc2_w, const float* __restrict__ fc2_b,
             float* __restrict__ out)
{
    __shared__ float w1[FC1 * HDIM];
    __shared__ float b1[FC1];
    __shared__ float w2[FC1];
    const int tid = threadIdx.x;
    for (int i = tid; i < FC1 * HDIM; i += 256) w1[i] = fc1_w[i];
    if (tid < FC1) { b1[tid] = fc1_b[tid]; w2[tid] = fc2_w[tid]; }
    __syncthreads();

    const int b = blockIdx.x * 256 + tid;
    const size_t base = ((size_t)b * T_LEN + (T_LEN - 1)) * HDIM;
    float h[HDIM];
#pragma unroll
    for (int q = 0; q < HDIM; ++q) {
      unsigned int v = seqp[base + q];
      float hi = (float)__builtin_bit_cast(__bf16, (unsigned short)(v & 0xffffu));
      float lo = (float)__builtin_bit_cast(__bf16, (unsigned short)(v >> 16));
      h[q] = hi + lo;
    }
    float acc2 = fc2_b[0];
    for (int m = 0; m < FC1; ++m) {
      float a = b1[m];
#pragma unroll
      for (int q = 0; q < HDIM; ++q) a += w1[m * HDIM + q] * h[q];
      acc2 += w2[m] * fmaxf(a, 0.0f);
    }
    out[b] = acc2;
}

extern "C" void kernel_launch(void* const* d_in, const int* in_sizes, int n_in,
                              void* d_out, int out_size, void* d_ws, size_t ws_size,
                              hipStream_t stream) {
    const float* x         = (const float*)d_in[0];
    const float* w_ih0     = (const float*)d_in[1];
    const float* w_ih_rest = (const float*)d_in[2];
    const float* w_hh      = (const float*)d_in[3];
    const float* b_ih      = (const float*)d_in[4];
    const float* b_hh      = (const float*)d_in[5];
    const float* fc1_w     = (const float*)d_in[6];
    const float* fc1_b     = (const float*)d_in[7];
    const float* fc2_w     = (const float*)d_in[8];
    const float* fc2_b     = (const float*)d_in[9];
    float* out = (float*)d_out;

    unsigned int* seqp = (unsigned int*)d_ws;   // [B,T,64] packed = 256 MiB

    lstm_mfma<true><<<dim3(B_TOT / 16), dim3(256), 0, stream>>>(
        x, w_ih0, w_hh, b_ih, b_hh, seqp);
    for (int l = 1; l < 5; ++l) {
      lstm_mfma<false><<<dim3(B_TOT / 16), dim3(256), 0, stream>>>(
          nullptr,
          w_ih_rest + (size_t)(l - 1) * 256 * HDIM,
          w_hh + (size_t)l * 256 * HDIM,
          b_ih + (size_t)l * 256,
          b_hh + (size_t)l * 256,
          seqp);
    }
    fc_head<<<dim3(B_TOT / 256), dim3(256), 0, stream>>>(
        seqp, fc1_w, fc1_b, fc2_w, fc2_b, out);
}

// Round 5
// 2746.768 us; speedup vs baseline: 1.2324x; 1.2324x over previous
//
#include <hip/hip_runtime.h>
#include <math.h>

#define B_TOT 2048
#define T_LEN 512
#define HDIM 64
#define FC1 50

typedef __bf16 bf16x8 __attribute__((ext_vector_type(8)));
typedef float f32x4 __attribute__((ext_vector_type(4)));
typedef unsigned int u32x4 __attribute__((ext_vector_type(4)));

__device__ __forceinline__ float sigm(float x) { return 1.0f / (1.0f + __expf(-x)); }
__device__ __forceinline__ float tanh_(float x) { return 2.0f / (1.0f + __expf(-2.0f * x)) - 1.0f; }

// lgkm-only barrier: LDS visibility without draining global stores/loads.
#define BARRIER() asm volatile("s_waitcnt lgkmcnt(0)\n\ts_barrier" ::: "memory")

#define MFMA __builtin_amdgcn_mfma_f32_16x16x32_bf16

// Unpack 8 packed u32 (hi|lo<<16 bf16 pair) into hi-plane / lo-plane bf16x8.
// Bit-identical to R3/R4's element-wise unpack, but explicit v_perm_b32.
__device__ __forceinline__ void unpk(u32x4 p0, u32x4 p1, bf16x8* hi, bf16x8* lo) {
  u32x4 h, l;
  h[0] = __builtin_amdgcn_perm(p0[1], p0[0], 0x05040100u);
  h[1] = __builtin_amdgcn_perm(p0[3], p0[2], 0x05040100u);
  h[2] = __builtin_amdgcn_perm(p1[1], p1[0], 0x05040100u);
  h[3] = __builtin_amdgcn_perm(p1[3], p1[2], 0x05040100u);
  l[0] = __builtin_amdgcn_perm(p0[1], p0[0], 0x07060302u);
  l[1] = __builtin_amdgcn_perm(p0[3], p0[2], 0x07060302u);
  l[2] = __builtin_amdgcn_perm(p1[1], p1[0], 0x07060302u);
  l[3] = __builtin_amdgcn_perm(p1[3], p1[2], 0x07060302u);
  *hi = __builtin_bit_cast(bf16x8, h);
  *lo = __builtin_bit_cast(bf16x8, l);
}

// Producer/consumer split LSTM step. Block = 16 batch rows, 8 waves.
// Waves 0-3 (A): recurrence — ds_read h(t-1) frags, 16 h-MFMAs seeded from
//   accx[P] (bias + x-part, made by B last step), gate epilogue, ds_write h(t).
// Waves 4-7 (B): store h(t-1) to global; compute accx[1-P] = bias + x(t+1)
//   MFMAs; prefetch x(t+3) from global. No global ops in A at all.
#define STEP(T0, P)                                                            \
  {                                                                            \
    if (isA) {                                                                 \
      const int swz = (nn & 7) << 2;                                           \
      bf16x8 ahh0, ahl0, ahh1, ahl1;                                           \
      {                                                                        \
        u32x4 p0 = *(const u32x4*)&hbuf[P][nn * 64 + ((8 * cg) ^ swz)];        \
        u32x4 p1 = *(const u32x4*)&hbuf[P][nn * 64 + ((8 * cg + 4) ^ swz)];    \
        unpk(p0, p1, &ahh0, &ahl0);                                            \
      }                                                                        \
      {                                                                        \
        u32x4 p0 = *(const u32x4*)&hbuf[P][nn * 64 + ((32 + 8 * cg) ^ swz)];   \
        u32x4 p1 = *(const u32x4*)&hbuf[P][nn * 64 + ((32 + 8 * cg + 4) ^ swz)];\
        unpk(p0, p1, &ahh1, &ahl1);                                            \
      }                                                                        \
      f32x4 accs[4];                                                           \
      _Pragma("unroll")                                                        \
      for (int g = 0; g < 4; ++g) {                                            \
        f32x4 a = accx[P][g][wq * 64 + lane];                                  \
        a = MFMA(ahh0, bhh[g][0], a, 0, 0, 0);                                 \
        a = MFMA(ahh1, bhh[g][1], a, 0, 0, 0);                                 \
        a = MFMA(ahl0, bhh[g][0], a, 0, 0, 0);                                 \
        a = MFMA(ahl1, bhh[g][1], a, 0, 0, 0);                                 \
        accs[g] = a;                                                           \
      }                                                                        \
      _Pragma("unroll")                                                        \
      for (int r = 0; r < 4; ++r) {                                            \
        float iv = sigm(accs[0][r]);                                           \
        float fv = sigm(accs[1][r]);                                           \
        float gv = tanh_(accs[2][r]);                                          \
        float ov = sigm(accs[3][r]);                                           \
        cell[r] = fv * cell[r] + iv * gv;                                      \
        float hv = ov * tanh_(cell[r]);                                        \
        __bf16 h1 = (__bf16)hv;                                                \
        __bf16 h2 = (__bf16)(hv - (float)h1);                                  \
        unsigned int hb = (unsigned int)__builtin_bit_cast(unsigned short, h1) \
                        | ((unsigned int)__builtin_bit_cast(unsigned short, h2) << 16); \
        int mrow = 4 * cg + r;                                                 \
        hbuf[1 - (P)][mrow * 64 + (uu ^ ((mrow & 7) << 2))] = hb;              \
      }                                                                        \
    } else {                                                                   \
      if ((T0) > 0) {                                                          \
        _Pragma("unroll")                                                      \
        for (int r = 0; r < 4; ++r) {                                          \
          int mrow = 4 * cg + r;                                               \
          unsigned int v = hbuf[P][mrow * 64 + (uu ^ ((mrow & 7) << 2))];      \
          seqp[((size_t)(bbase + mrow) * T_LEN + (T0) - 1) * HDIM + uu] = v;   \
        }                                                                      \
      }                                                                        \
      if ((T0) + 1 < T_LEN) {                                                  \
        if (FIRST) {                                                           \
          _Pragma("unroll")                                                    \
          for (int g = 0; g < 4; ++g) {                                        \
            f32x4 a;                                                           \
            _Pragma("unroll")                                                  \
            for (int r = 0; r < 4; ++r)                                        \
              a[r] = bias[g] + xw[g*3+0] * xr[P][r*3+0]                        \
                             + xw[g*3+1] * xr[P][r*3+1]                        \
                             + xw[g*3+2] * xr[P][r*3+2];                       \
            accx[1 - (P)][g][wq * 64 + lane] = a;                              \
          }                                                                    \
        } else {                                                               \
          bf16x8 xh0, xl0, xh1, xl1;                                           \
          unpk(xpk[P][0], xpk[P][1], &xh0, &xl0);                              \
          unpk(xpk[P][2], xpk[P][3], &xh1, &xl1);                              \
          _Pragma("unroll")                                                    \
          for (int g = 0; g < 4; ++g) {                                        \
            f32x4 a = {bias[g], bias[g], bias[g], bias[g]};                    \
            a = MFMA(xh0, bih[g][0], a, 0, 0, 0);                              \
            a = MFMA(xh1, bih[g][1], a, 0, 0, 0);                              \
            a = MFMA(xl0, bih[g][0], a, 0, 0, 0);                              \
            a = MFMA(xl1, bih[g][1], a, 0, 0, 0);                              \
            accx[1 - (P)][g][wq * 64 + lane] = a;                              \
          }                                                                    \
        }                                                                      \
      }                                                                        \
      {                                                                        \
        int tp = (T0) + 3; if (tp >= T_LEN) tp = T_LEN - 1;                    \
        if (FIRST) {                                                           \
          _Pragma("unroll")                                                    \
          for (int r = 0; r < 4; ++r)                                          \
            _Pragma("unroll")                                                  \
            for (int i = 0; i < 3; ++i)                                        \
              xr[P][r*3+i] = x_f32[((size_t)(bbase + 4*cg + r) * T_LEN + tp) * 3 + i]; \
        } else {                                                               \
          const unsigned int* px = seqp + xrow + (size_t)tp * HDIM;            \
          xpk[P][0] = *(const u32x4*)(px + 8 * cg);                            \
          xpk[P][1] = *(const u32x4*)(px + 8 * cg + 4);                        \
          xpk[P][2] = *(const u32x4*)(px + 32 + 8 * cg);                       \
          xpk[P][3] = *(const u32x4*)(px + 32 + 8 * cg + 4);                   \
        }                                                                      \
      }                                                                        \
    }                                                                          \
    BARRIER();                                                                 \
  }

template<bool FIRST>
__global__ __launch_bounds__(512, 2)
void lstm_mfma(const float* __restrict__ x_f32,  // FIRST only: [B,T,3] f32
               const float* __restrict__ w_ih,   // FIRST: [256,3] else [256,64]
               const float* __restrict__ w_hh,   // [256,64]
               const float* __restrict__ b_ih,   // [256]
               const float* __restrict__ b_hh,   // [256]
               unsigned int* seqp)               // [B,T,64] packed hi|lo<<16 (in-place for mid)
{
    const int tid  = threadIdx.x;
    const int lane = tid & 63;
    const int wv   = tid >> 6;      // 0..7
    const bool isA = (wv < 4);
    const int wq   = wv & 3;        // unit-block index within group
    const int nn   = lane & 15;     // A-row m (batch) / B-col n (gate col)
    const int cg   = lane >> 4;     // k-group / D row group
    const int bbase = blockIdx.x * 16;
    const int grow = 16 * wq + nn;  // unit / gate-col index
    const int uu   = grow;

    __shared__ __align__(16) unsigned int hbuf[2][16 * 64];  // 8 KB
    __shared__ __align__(16) f32x4 accx[2][4][256];          // 32 KB

    // ---- weights ----
    bf16x8 bhh[4][2];
    bf16x8 bih[4][2];
    float xw[12];
    float bias[4];
    if (isA) {
#pragma unroll
      for (int g = 0; g < 4; ++g)
#pragma unroll
        for (int kk = 0; kk < 2; ++kk) {
          const float* wp = w_hh + (size_t)(64 * g + grow) * 64 + kk * 32 + 8 * cg;
#pragma unroll
          for (int e = 0; e < 8; ++e) bhh[g][kk][e] = (__bf16)wp[e];
        }
    } else {
#pragma unroll
      for (int g = 0; g < 4; ++g) {
        int row = 64 * g + grow;
        bias[g] = b_ih[row] + b_hh[row];
      }
      if (FIRST) {
#pragma unroll
        for (int g = 0; g < 4; ++g)
#pragma unroll
          for (int i = 0; i < 3; ++i) xw[g * 3 + i] = w_ih[(64 * g + grow) * 3 + i];
      } else {
#pragma unroll
        for (int g = 0; g < 4; ++g)
#pragma unroll
          for (int kk = 0; kk < 2; ++kk) {
            const float* wp = w_ih + (size_t)(64 * g + grow) * 64 + kk * 32 + 8 * cg;
#pragma unroll
            for (int e = 0; e < 8; ++e) bih[g][kk][e] = (__bf16)wp[e];
          }
      }
    }

    for (int q = tid; q < 16 * 64; q += 512) hbuf[0][q] = 0u;

    float cell[4] = {0.f, 0.f, 0.f, 0.f};

    const size_t xrow = (size_t)(bbase + nn) * T_LEN * HDIM;
    u32x4 xpk[2][4];
    float xr[2][12];

    if (!isA) {
      // ---- prologue: accx[0] from x(0); prime xr/xpk = x(1), x(2) ----
      if (FIRST) {
        float x0[12];
#pragma unroll
        for (int r = 0; r < 4; ++r)
#pragma unroll
          for (int i = 0; i < 3; ++i)
            x0[r*3+i] = x_f32[((size_t)(bbase + 4*cg + r) * T_LEN + 0) * 3 + i];
#pragma unroll
        for (int g = 0; g < 4; ++g) {
          f32x4 a;
#pragma unroll
          for (int r = 0; r < 4; ++r)
            a[r] = bias[g] + xw[g*3+0]*x0[r*3+0] + xw[g*3+1]*x0[r*3+1] + xw[g*3+2]*x0[r*3+2];
          accx[0][g][wq * 64 + lane] = a;
        }
#pragma unroll
        for (int p = 0; p < 2; ++p)
#pragma unroll
          for (int r = 0; r < 4; ++r)
#pragma unroll
            for (int i = 0; i < 3; ++i)
              xr[p][r*3+i] = x_f32[((size_t)(bbase + 4*cg + r) * T_LEN + (p + 1)) * 3 + i];
      } else {
        const unsigned int* px = seqp + xrow;
        u32x4 q0 = *(const u32x4*)(px + 8 * cg);
        u32x4 q1 = *(const u32x4*)(px + 8 * cg + 4);
        u32x4 q2 = *(const u32x4*)(px + 32 + 8 * cg);
        u32x4 q3 = *(const u32x4*)(px + 32 + 8 * cg + 4);
        bf16x8 xh0, xl0, xh1, xl1;
        unpk(q0, q1, &xh0, &xl0);
        unpk(q2, q3, &xh1, &xl1);
#pragma unroll
        for (int g = 0; g < 4; ++g) {
          f32x4 a = {bias[g], bias[g], bias[g], bias[g]};
          a = MFMA(xh0, bih[g][0], a, 0, 0, 0);
          a = MFMA(xh1, bih[g][1], a, 0, 0, 0);
          a = MFMA(xl0, bih[g][0], a, 0, 0, 0);
          a = MFMA(xl1, bih[g][1], a, 0, 0, 0);
          accx[0][g][wq * 64 + lane] = a;
        }
#pragma unroll
        for (int p = 0; p < 2; ++p) {
          const unsigned int* pq = seqp + xrow + (size_t)(p + 1) * HDIM;
          xpk[p][0] = *(const u32x4*)(pq + 8 * cg);
          xpk[p][1] = *(const u32x4*)(pq + 8 * cg + 4);
          xpk[p][2] = *(const u32x4*)(pq + 32 + 8 * cg);
          xpk[p][3] = *(const u32x4*)(pq + 32 + 8 * cg + 4);
        }
      }
    }
    __syncthreads();

    for (int t = 0; t < T_LEN; t += 2) {
      STEP(t, 0);
      STEP(t + 1, 1);
    }

    // tail: store h(T-1) (written to hbuf[0] by step 511)
    if (!isA) {
#pragma unroll
      for (int r = 0; r < 4; ++r) {
        int mrow = 4 * cg + r;
        unsigned int v = hbuf[0][mrow * 64 + (uu ^ ((mrow & 7) << 2))];
        seqp[((size_t)(bbase + mrow) * T_LEN + (T_LEN - 1)) * HDIM + uu] = v;
      }
    }
}

// FC head: out[b] = fc2_b + fc2_w . relu(fc1_b + fc1_w . h_T[b])
__global__ __launch_bounds__(256, 1)
void fc_head(const unsigned int* __restrict__ seqp,
             const float* __restrict__ fc1_w, const float* __restrict__ fc1_b,
             const float* __restrict__ fc2_w, const float* __restrict__ fc2_b,
             float* __restrict__ out)
{
    __shared__ float w1[FC1 * HDIM];
    __shared__ float b1[FC1];
    __shared__ float w2[FC1];
    const int tid = threadIdx.x;
    for (int i = tid; i < FC1 * HDIM; i += 256) w1[i] = fc1_w[i];
    if (tid < FC1) { b1[tid] = fc1_b[tid]; w2[tid] = fc2_w[tid]; }
    __syncthreads();

    const int b = blockIdx.x * 256 + tid;
    const size_t base = ((size_t)b * T_LEN + (T_LEN - 1)) * HDIM;
    float h[HDIM];
#pragma unroll
    for (int q = 0; q < HDIM; ++q) {
      unsigned int v = seqp[base + q];
      float hi = (float)__builtin_bit_cast(__bf16, (unsigned short)(v & 0xffffu));
      float lo = (float)__builtin_bit_cast(__bf16, (unsigned short)(v >> 16));
      h[q] = hi + lo;
    }
    float acc2 = fc2_b[0];
    for (int m = 0; m < FC1; ++m) {
      float a = b1[m];
#pragma unroll
      for (int q = 0; q < HDIM; ++q) a += w1[m * HDIM + q] * h[q];
      acc2 += w2[m] * fmaxf(a, 0.0f);
    }
    out[b] = acc2;
}

extern "C" void kernel_launch(void* const* d_in, const int* in_sizes, int n_in,
                              void* d_out, int out_size, void* d_ws, size_t ws_size,
                              hipStream_t stream) {
    const float* x         = (const float*)d_in[0];
    const float* w_ih0     = (const float*)d_in[1];
    const float* w_ih_rest = (const float*)d_in[2];
    const float* w_hh      = (const float*)d_in[3];
    const float* b_ih      = (const float*)d_in[4];
    const float* b_hh      = (const float*)d_in[5];
    const float* fc1_w     = (const float*)d_in[6];
    const float* fc1_b     = (const float*)d_in[7];
    const float* fc2_w     = (const float*)d_in[8];
    const float* fc2_b     = (const float*)d_in[9];
    float* out = (float*)d_out;

    unsigned int* seqp = (unsigned int*)d_ws;   // [B,T,64] packed = 256 MiB

    lstm_mfma<true><<<dim3(B_TOT / 16), dim3(512), 0, stream>>>(
        x, w_ih0, w_hh, b_ih, b_hh, seqp);
    for (int l = 1; l < 5; ++l) {
      lstm_mfma<false><<<dim3(B_TOT / 16), dim3(512), 0, stream>>>(
          nullptr,
          w_ih_rest + (size_t)(l - 1) * 256 * HDIM,
          w_hh + (size_t)l * 256 * HDIM,
          b_ih + (size_t)l * 256,
          b_hh + (size_t)l * 256,
          seqp);
    }
    fc_head<<<dim3(B_TOT / 256), dim3(256), 0, stream>>>(
        seqp, fc1_w, fc1_b, fc2_w, fc2_b, out);
}